// Round 2
// baseline (487.098 us; speedup 1.0000x reference)
//
#include <hip/hip_runtime.h>
#include <hip/hip_bf16.h>

// KronLinear: out = x @ (sum_r kron(a_r, b_r)) + bias
// M=8192 tokens, K=4096=(i,k_b), N=4096=(j,l), RANK=64.
// R4: (a) pack-x rewritten: block = 16 consecutive rows x full K ->
//     fully contiguous 256KB DRAM reads (old version read 128B @ 16KB
//     stride = DRAM worst case, ~0.85 TB/s). Xp chunk order changed to
//     (mm*4+c); gemm compensates with per-lane pre-swizzled global src
//     for global_load_lds (LDS image unchanged).
// (b) gemm prefetch depth 2 -> 3 (ring is 4-deep): vmcnt(8), step t+1
//     now has ~2 iterations to land (covers L3/HBM latency).

#define M_DIM 8192
#define N_DIM 4096
#define K_DIM 4096
#define KT_COUNT 128   // K_DIM / 32
#define NPACK 512      // pack blocks: 8192 rows / 16

typedef __attribute__((ext_vector_type(8))) short short8;
typedef __attribute__((ext_vector_type(4))) float floatx4;

typedef __attribute__((address_space(1))) void gvoid_t;
typedef __attribute__((address_space(3))) void lvoid_t;

static __device__ __forceinline__ void gl_lds16(const void* g, const void* l) {
  __builtin_amdgcn_global_load_lds((gvoid_t*)(unsigned long long)g,
                                   (lvoid_t*)(unsigned int)(unsigned long long)l,
                                   16, 0, 0);
}

static __device__ __forceinline__ unsigned short f2bf(float f) {
  unsigned int u = __builtin_bit_cast(unsigned int, f);
  u = (u + 0x7fffu + ((u >> 16) & 1u)) >> 16;  // RNE
  return (unsigned short)u;
}

// ---------------------------------------------------------------------------
// Fused prep, 512-thread blocks.
// blocks [0, NPACK): pack x. Block owns 16 consecutive rows x full K.
//   Read: thread t reads 32B at x[row][t*8] -> wave reads 2KB contiguous.
//   Write: thread t owns (kt = t>>2, c = t&3); row mm writes 16B at chunk
//   (mm*4 + c) -> 64B runs, rows ascending -> L2 write-combines lines.
// blocks [NPACK, NPACK+2048): build W^T, original 256-thread code (threads
//   256..511 idle; single unconditional barrier keeps it legal).
//
// Xp blob (M0, kt) = 8KB: chunk (mm*4 + c) holds row M0*128+mm,
// k = kt*32 + c*8 .. +7 as 8 bf16.
// Wp blob unchanged: chunk (c*128 + n) holds col n, same k split.
// ---------------------------------------------------------------------------
__global__ __launch_bounds__(512) void prep_kernel(
    const float* __restrict__ x, const float* __restrict__ a,
    const float* __restrict__ b, unsigned short* __restrict__ Xp,
    unsigned short* __restrict__ Wp) {
  __shared__ float lds_a[1024];
  const int bid = blockIdx.x;
  const int t = threadIdx.x;

  if (bid < NPACK) {
    // ---- pack x: 16 rows, fully contiguous reads
    const int M0 = bid >> 3;
    const int mm0 = (bid & 7) * 16;
    const int kt = t >> 2, c = t & 3;
    const float* src = x + (size_t)(M0 * 128 + mm0) * K_DIM + t * 8;
    unsigned short* dst =
        Xp + (size_t)(M0 * KT_COUNT + kt) * 4096 + (mm0 * 4 + c) * 8;
#pragma unroll 4
    for (int r = 0; r < 16; ++r) {
      float4 v0 = ((const float4*)src)[0];
      float4 v1 = ((const float4*)src)[1];
      short8 o;
      o[0] = (short)f2bf(v0.x); o[1] = (short)f2bf(v0.y);
      o[2] = (short)f2bf(v0.z); o[3] = (short)f2bf(v0.w);
      o[4] = (short)f2bf(v1.x); o[5] = (short)f2bf(v1.y);
      o[6] = (short)f2bf(v1.z); o[7] = (short)f2bf(v1.w);
      *(short8*)dst = o;
      src += K_DIM;
      dst += 32;  // next row: +4 chunks = 64B
    }
  } else {
    // ---- build W^T: wT[n=(j*64+l)][i*64+k_b] = sum_r a[r,i,j]*b[r,k_b,l]
    const int bw = bid - NPACK;
    const int rg = bw & 255;
    const int i = rg >> 2;
    const int j0 = (rg & 3) * 16;
    const int k0 = (bw >> 8) * 8;  // 0..56

    if (t < 256) {  // stage a[r, i, j0..j0+15] for all r: 1024 floats
      const int r = t >> 2, jq = t & 3;
      float4 v = ((const float4*)(a + (size_t)r * 4096 + i * 64 + j0))[jq];
      ((float4*)lds_a)[r * 4 + jq] = v;
    }
    __syncthreads();

    if (t < 256) {
      const int l = t & 63;
      const int jj = t >> 6;  // 0..3
      float acc[4][8];
#pragma unroll
      for (int jp = 0; jp < 4; ++jp)
#pragma unroll
        for (int kb = 0; kb < 8; ++kb) acc[jp][kb] = 0.f;

      const float* bb = b + k0 * 64 + l;
#pragma unroll 4
      for (int r = 0; r < 64; ++r) {
        float4 aj = ((const float4*)lds_a)[r * 4 + jj];
        float bv[8];
#pragma unroll
        for (int kb = 0; kb < 8; ++kb) bv[kb] = bb[(size_t)r * 4096 + kb * 64];
        const float av[4] = {aj.x, aj.y, aj.z, aj.w};
#pragma unroll
        for (int jp = 0; jp < 4; ++jp)
#pragma unroll
          for (int kb = 0; kb < 8; ++kb)
            acc[jp][kb] = fmaf(av[jp], bv[kb], acc[jp][kb]);
      }

      const int kt = (i * 64 + k0) >> 5;
      const int c = (k0 & 31) >> 3;
#pragma unroll
      for (int jp = 0; jp < 4; ++jp) {
        const int j = j0 + jj * 4 + jp;
        const int n = j * 64 + l;
        const int blob = (n >> 7) * KT_COUNT + kt;
        const int pos = c * 128 + (n & 127);
        short8 o;
#pragma unroll
        for (int kb = 0; kb < 8; ++kb) o[kb] = (short)f2bf(acc[jp][kb]);
        *(short8*)(Wp + (size_t)blob * 4096 + pos * 8) = o;
      }
    }
  }
}

// ---------------------------------------------------------------------------
// GEMM: C = Xp @ Wp^T + bias.  256x256 tile, BK=32, 512 threads (8 waves,
// 2M x 4N), per-wave 128x64 output = acc[8][4] of 16x16 frags.
// LDS: 4-deep ring of K-steps (A 16KB + B 16KB each) = 128 KiB.
// Prefetch distance 3: issue step t+3, single counted vmcnt(8)/K-step
// (8 loads in flight = steps t+2,t+3; forces t+1 landed, ~2 iters of slack).
// Ring-overlap safe: write target (kt+3)&3 = buffer last read at kt-1,
// drained by that iteration's lgkmcnt(0) + trailing barrier.
// A-side global src per-lane permuted for the new Xp chunk order (mm*4+c):
// LDS chunk t must hold (c = t>>7, mm = t&127) -> src chunk (t&127)*4+(t>>7).
// XCD swizzle: bid&7 -> XCD owns 2 N-panels (4MB Wp slice pinned in its L2).
// ---------------------------------------------------------------------------
#define BAR() asm volatile("s_barrier" ::: "memory")
#define WAIT_VM(N) asm volatile("s_waitcnt vmcnt(" #N ")" ::: "memory")
#define WAIT_LGKM0() asm volatile("s_waitcnt lgkmcnt(0)" ::: "memory")

__global__ __launch_bounds__(512, 2) void gemm_kernel(
    const unsigned short* __restrict__ Xp, const unsigned short* __restrict__ Wp,
    const float* __restrict__ bias, float* __restrict__ out) {
  __shared__ short8 As[4][2][512];  // [ring buf][row half][chunk]  64 KiB
  __shared__ short8 Bs[4][2][512];  // [ring buf][col half][chunk]  64 KiB

  const int bid = blockIdx.x;
  const int xcd = bid & 7;
  const int pos = bid >> 3;            // 0..63
  const int N0 = xcd * 2 + (pos & 1);  // 0..15 (256-col panels)
  const int M0 = pos >> 1;             // 0..31 (256-row panels)

  const int t = threadIdx.x;
  const int wave = t >> 6, lane = t & 63;
  const int l16 = lane & 15, quad = lane >> 4;
  const int wm = wave & 1;   // A half (128 rows)
  const int wn = wave >> 1;  // 0..3 (64-col quarter)

  floatx4 acc[8][4];
#pragma unroll
  for (int mt = 0; mt < 8; ++mt)
#pragma unroll
    for (int nt = 0; nt < 4; ++nt) acc[mt][nt] = (floatx4){0.f, 0.f, 0.f, 0.f};

  const int pt = ((t & 127) << 2) | (t >> 7);  // A-side lane permutation
  const unsigned short* gA0 = Xp + (size_t)(M0 * 2 + 0) * KT_COUNT * 4096 + (size_t)pt * 8;
  const unsigned short* gA1 = Xp + (size_t)(M0 * 2 + 1) * KT_COUNT * 4096 + (size_t)pt * 8;
  const unsigned short* gB0 = Wp + (size_t)(N0 * 2 + 0) * KT_COUNT * 4096 + (size_t)t * 8;
  const unsigned short* gB1 = Wp + (size_t)(N0 * 2 + 1) * KT_COUNT * 4096 + (size_t)t * 8;

  // ---- prologue: stage K-steps 0,1,2 (12 loads); require step 0 landed.
#pragma unroll
  for (int s = 0; s < 3; ++s) {
    gl_lds16(gA0 + (size_t)s * 4096, &As[s][0][t]);
    gl_lds16(gA1 + (size_t)s * 4096, &As[s][1][t]);
    gl_lds16(gB0 + (size_t)s * 4096, &Bs[s][0][t]);
    gl_lds16(gB1 + (size_t)s * 4096, &Bs[s][1][t]);
  }
  WAIT_VM(8);  // step 0 complete; steps 1,2 (8 loads) may stay in flight
  BAR();

  const int ra = quad * 128 + l16;                  // A chunk base
  const int rb = quad * 128 + (wn & 1) * 64 + l16;  // B chunk base
  const int bh = wn >> 1;                           // B half

#pragma unroll 2
  for (int kt = 0; kt < KT_COUNT; ++kt) {
    const int tb = kt & 3;
    const int db = (kt + 3) & 3;
    const size_t soff =
        (size_t)((kt + 3 < KT_COUNT) ? kt + 3 : KT_COUNT - 1) * 4096;

    short8 bf[4], af[4];

    // ---------------- phase 0: B frags + A rows 0..63, stage A(t+3)
#pragma unroll
    for (int nt = 0; nt < 4; ++nt) bf[nt] = Bs[tb][bh][rb + nt * 16];
#pragma unroll
    for (int m = 0; m < 4; ++m) af[m] = As[tb][wm][ra + m * 16];
    gl_lds16(gA0 + soff, &As[db][0][t]);
    gl_lds16(gA1 + soff, &As[db][1][t]);
    BAR();
    WAIT_LGKM0();
    __builtin_amdgcn_sched_barrier(0);
    __builtin_amdgcn_s_setprio(1);
#pragma unroll
    for (int m = 0; m < 4; ++m)
#pragma unroll
      for (int nt = 0; nt < 4; ++nt)
        acc[m][nt] = __builtin_amdgcn_mfma_f32_16x16x32_bf16(
            af[m], bf[nt], acc[m][nt], 0, 0, 0);
    __builtin_amdgcn_s_setprio(0);
    __builtin_amdgcn_sched_barrier(0);
    BAR();

    // ---------------- phase 1: A rows 64..127, stage B(t+3), counted vmcnt
#pragma unroll
    for (int m = 0; m < 4; ++m) af[m] = As[tb][wm][ra + (4 + m) * 16];
    gl_lds16(gB0 + soff, &Bs[db][0][t]);
    gl_lds16(gB1 + soff, &Bs[db][1][t]);
    WAIT_VM(8);  // steps t+2,t+3 in flight; forces step t+1 landed
    BAR();
    WAIT_LGKM0();
    __builtin_amdgcn_sched_barrier(0);
    __builtin_amdgcn_s_setprio(1);
#pragma unroll
    for (int m = 0; m < 4; ++m)
#pragma unroll
      for (int nt = 0; nt < 4; ++nt)
        acc[4 + m][nt] = __builtin_amdgcn_mfma_f32_16x16x32_bf16(
            af[m], bf[nt], acc[4 + m][nt], 0, 0, 0);
    __builtin_amdgcn_s_setprio(0);
    __builtin_amdgcn_sched_barrier(0);
    BAR();
  }

  // ---- epilogue
  const int col_base = N0 * 256 + wn * 64;
  const int row_base = M0 * 256 + wm * 128;
#pragma unroll
  for (int nt = 0; nt < 4; ++nt) {
    const int col = col_base + nt * 16 + l16;
    const float bv = bias[col];
#pragma unroll
    for (int mt = 0; mt < 8; ++mt) {
      floatx4 v = acc[mt][nt];
#pragma unroll
      for (int r4 = 0; r4 < 4; ++r4) {
        const int row = row_base + mt * 16 + quad * 4 + r4;
        out[(size_t)row * N_DIM + col] = v[r4] + bv;
      }
    }
  }
}

extern "C" void kernel_launch(void* const* d_in, const int* in_sizes, int n_in,
                              void* d_out, int out_size, void* d_ws, size_t ws_size,
                              hipStream_t stream) {
  const float* x = (const float*)d_in[0];     // 8192*4096
  const float* a = (const float*)d_in[1];     // 64*64*64 (r,i,j)
  const float* b = (const float*)d_in[2];     // 64*64*64 (r,k,l)
  const float* bias = (const float*)d_in[3];  // 4096
  float* out = (float*)d_out;

  unsigned short* Xp = (unsigned short*)d_ws;        // 67MB
  unsigned short* Wp = Xp + (size_t)M_DIM * K_DIM;   // 33.5MB

  prep_kernel<<<NPACK + 2048, 512, 0, stream>>>(x, a, b, Xp, Wp);
  gemm_kernel<<<512, 512, 0, stream>>>(Xp, Wp, bias, out);
}